// Round 5
// baseline (137.965 us; speedup 1.0000x reference)
//
#include <hip/hip_runtime.h>
#include <hip/hip_bf16.h>

// Problem constants (fixed shapes from the reference)
#define DIN   2048
#define DOUT  2048
#define NTOK  2048
#define NE    8
#define TOPK  2
#define NK    (NTOK*TOPK)       // 4096 flat (token,slot) rows
#define BM    256
#define BN    256
#define KSPLIT 2
#define KLOC  (DIN/KSPLIT)      // 1024 K per block
#define NSLICE (KLOC/32)        // 32 K-units of 32 cols
#define MAXMT (NK/BM + NE)      // 24 worst-case M-tiles
#define NTN   (DOUT/BN)         // 8 N-tiles
#define NBLK  (MAXMT*NTN*KSPLIT) // 384 (multiple of 8)

#define WEL   (NE*DOUT*DIN)     // 33554432 weight elements
#define XEL   (NTOK*DIN)        // 4194304 input elements

typedef unsigned short u16;
typedef __attribute__((ext_vector_type(8))) short bf16x8;
typedef __attribute__((ext_vector_type(4))) float f32x4;

// fp32 -> bf16 pair pack: round-half-away (add 0x8000), v_perm grabs high halves.
__device__ __forceinline__ unsigned pack2rn(float a, float b) {
    union { float f; unsigned u; } x, y; x.f = a; y.f = b;
    return __builtin_amdgcn_perm(y.u + 0x8000u, x.u + 0x8000u, 0x07060302u);
}

// async global -> LDS, 16 bytes/lane (wave-uniform LDS base + lane*16; global addr per-lane)
__device__ __forceinline__ void gl_lds16(const void* g, void* l) {
    __builtin_amdgcn_global_load_lds(
        (const __attribute__((address_space(1))) void*)g,
        (__attribute__((address_space(3)))       void*)l, 16, 0, 0);
}

// ---------------- Pass 1: fp32 -> bf16 convert (weight + inputs) ----------------
__global__ __launch_bounds__(256) void cvt_bf16(
    const float* __restrict__ w, const float* __restrict__ x,
    u16* __restrict__ wbf, u16* __restrict__ xbf)
{
    const size_t nch = (size_t)(WEL + XEL) / 8;
    for (size_t c = (size_t)blockIdx.x * blockDim.x + threadIdx.x; c < nch;
         c += (size_t)gridDim.x * blockDim.x) {
        const float* src; u16* dst; size_t off;
        if (c < (size_t)WEL / 8) { src = w; dst = wbf; off = c * 8; }
        else                     { src = x; dst = xbf; off = (c - (size_t)WEL / 8) * 8; }
        float4 f0 = *(const float4*)(src + off);
        float4 f1 = *(const float4*)(src + off + 4);
        uint4 pk;
        pk.x = pack2rn(f0.x, f0.y); pk.y = pack2rn(f0.z, f0.w);
        pk.z = pack2rn(f1.x, f1.y); pk.w = pack2rn(f1.z, f1.w);
        *(uint4*)(dst + off) = pk;
    }
}

// ---------------- Pass 2: 256x256 grouped GEMM, 4-slot K-unit ring pipeline ----------------
// Unit = 32 K-cols of A(256 rows) + B(256 rows), 32 KB. Ring of 4 units in LDS.
// Phase u: vmcnt(counted) -> barrier -> issue unit u+3 -> 12 ds_read_b128 -> 32 MFMA.
// Race-free: slot (u+3)&3 was last read in phase u-1, whose reads retired before
// this phase's barrier; vmcnt-then-barrier guarantees unit u fully landed (all waves).
__global__ __launch_bounds__(512, 2) void moe_gemm8(
    const u16* __restrict__ xb,            // [NTOK][DIN] bf16
    const u16* __restrict__ wb,            // [NE][DOUT][DIN] bf16
    const int* __restrict__ sorted_scattered_idxs,
    const int* __restrict__ expert_offsets,
    const float* __restrict__ gates,
    float*     __restrict__ out)
{
    __shared__ u16 ring[4][2][256 * 32];   // [slot][A/B][row*32+col], 128 KiB
    __shared__ int   s_tok[BM];
    __shared__ float s_gate[BM];

    // XCD swizzle: 48 consecutive per XCD; n0 fastest so same-A-panel blocks share an XCD.
    const int bid = blockIdx.x;
    const int swz = (bid & 7) * (NBLK / 8) + (bid >> 3);
    const int n0  = (swz & (NTN - 1)) * BN;
    const int ksl = (swz >> 3) & (KSPLIT - 1);
    const int mt  = swz >> 4;

    int e = -1, m0 = 0, cnt = 0;
    {
        int acc = 0, prev = 0;
        for (int i = 0; i < NE; ++i) {
            int end = expert_offsets[i];
            int c = end - prev;
            int t = (c + BM - 1) / BM;
            if (mt < acc + t) {
                e = i; m0 = prev + (mt - acc) * BM;
                cnt = end - m0; if (cnt > BM) cnt = BM;
                break;
            }
            acc += t; prev = end;
        }
    }
    if (e < 0) return;   // tail blocks beyond real tile count (uniform exit, pre-barrier)

    const int tid = threadIdx.x;
    if (tid < BM) {
        int idx = (tid < cnt) ? (m0 + tid) : m0;   // clamp ragged rows to valid gather
        int p = sorted_scattered_idxs[idx];
        s_tok[tid]  = p;
        s_gate[tid] = gates[p];
    }
    __syncthreads();

    const int wid = tid >> 6, lane = tid & 63;
    const int kbase = ksl * KLOC;
    const u16* wbE = wb + (size_t)e * DOUT * DIN;

    // Staging sources: wave wid covers rows [q*128 + wid*16, +16), lane -> (row, chunk).
    // Source chunk pre-swizzled (c ^ ((row>>1)&3)) so LDS stays linear (rule 21) and
    // fragment ds_reads are 2-way-per-beat (free).
    const u16* aS[2]; const u16* bS[2];
    #pragma unroll
    for (int q = 0; q < 2; ++q) {
        int lrow = q * 128 + wid * 16 + (lane >> 2);
        int sc   = (lane & 3) ^ ((lane >> 3) & 3);   // (row>>1)&3 == (lane>>3)&3 here
        aS[q] = xb  + (size_t)(s_tok[lrow] >> 1) * DIN + kbase + sc * 8;
        bS[q] = wbE + (size_t)(n0 + lrow) * DIN + kbase + sc * 8;
    }

    // Fragment geometry: 8 waves as 2M x 4N; per-wave output 128x64.
    const int wr = wid >> 2, wc = wid & 3;
    const int lr = lane & 15, g = lane >> 4;
    const int cch = (g ^ ((lr >> 1) & 3)) * 8;       // swizzled K-chunk (u16 units)
    int aoff[8], boff[4];
    #pragma unroll
    for (int i = 0; i < 8; ++i) aoff[i] = (wr * 128 + i * 16 + lr) * 32 + cch;
    #pragma unroll
    for (int j = 0; j < 4; ++j) boff[j] = (wc * 64 + j * 16 + lr) * 32 + cch;

    f32x4 acc[8][4];
    #pragma unroll
    for (int i = 0; i < 8; ++i)
        #pragma unroll
        for (int j = 0; j < 4; ++j) acc[i][j] = (f32x4)0.0f;

#define STAGE(u)                                                            \
    {                                                                       \
        const int s_ = (u) & 3; const int ko = (u) * 32;                    \
        gl_lds16(aS[0] + ko, &ring[s_][0][(0 * 128 + wid * 16) * 32]);      \
        gl_lds16(aS[1] + ko, &ring[s_][0][(1 * 128 + wid * 16) * 32]);      \
        gl_lds16(bS[0] + ko, &ring[s_][1][(0 * 128 + wid * 16) * 32]);      \
        gl_lds16(bS[1] + ko, &ring[s_][1][(1 * 128 + wid * 16) * 32]);      \
    }

#define PHASE(u, VW)                                                        \
    {                                                                       \
        asm volatile("s_waitcnt vmcnt(" #VW ")" ::: "memory");              \
        __builtin_amdgcn_s_barrier();                                       \
        __builtin_amdgcn_sched_barrier(0);                                  \
        if ((u) + 3 < NSLICE) STAGE((u) + 3);                               \
        const u16* ab = &ring[(u) & 3][0][0];                               \
        const u16* bb = &ring[(u) & 3][1][0];                               \
        bf16x8 af[8], bfr[4];                                               \
        _Pragma("unroll")                                                   \
        for (int i = 0; i < 8; ++i) af[i] = *(const bf16x8*)(ab + aoff[i]); \
        _Pragma("unroll")                                                   \
        for (int j = 0; j < 4; ++j) bfr[j] = *(const bf16x8*)(bb + boff[j]);\
        __builtin_amdgcn_s_setprio(1);                                      \
        _Pragma("unroll")                                                   \
        for (int i = 0; i < 8; ++i)                                         \
            _Pragma("unroll")                                               \
            for (int j = 0; j < 4; ++j)                                     \
                acc[i][j] = __builtin_amdgcn_mfma_f32_16x16x32_bf16(        \
                    af[i], bfr[j], acc[i][j], 0, 0, 0);                     \
        __builtin_amdgcn_s_setprio(0);                                      \
        __builtin_amdgcn_sched_barrier(0);                                  \
    }

    // Prologue: 3 units in flight (12 loads/thread)
    STAGE(0); STAGE(1); STAGE(2);

    #pragma unroll 4
    for (int u = 0; u < NSLICE - 2; ++u) PHASE(u, 8);   // counted: 2 units stay in flight
    PHASE(NSLICE - 2, 4);                                // drain 4
    PHASE(NSLICE - 1, 0);                                // drain 0

#undef STAGE
#undef PHASE

    // Epilogue: out[token] += gate * y  (TOPK x KSPLIT contributions accumulate)
    #pragma unroll
    for (int i = 0; i < 8; ++i) {
        #pragma unroll
        for (int r = 0; r < 4; ++r) {
            int lrow = wr * 128 + i * 16 + g * 4 + r;
            if (lrow < cnt) {
                int   p  = s_tok[lrow];
                float gf = s_gate[lrow];
                float* orow = out + (size_t)(p >> 1) * DOUT + n0 + wc * 64;
                #pragma unroll
                for (int j = 0; j < 4; ++j)
                    atomicAdd(orow + j * 16 + lr, gf * acc[i][j][r]);
            }
        }
    }
}

// ---------------- Fallback: fused fp32-in kernel (used if ws too small) ----------------
#define FBM 128
#define FBK 64
__global__ __launch_bounds__(256, 3) void moe_gemm_fused(
    const float* __restrict__ inputs, const float* __restrict__ weight,
    const int* __restrict__ sorted_scattered_idxs, const int* __restrict__ expert_offsets,
    const float* __restrict__ gates, float* __restrict__ out)
{
    __shared__ u16 As[FBM * FBK];
    __shared__ u16 Bs[FBM * FBK];
    __shared__ int   s_tok[FBM];
    __shared__ float s_gate[FBM];

    const int mt = blockIdx.y;
    const int n0 = blockIdx.x * FBM;
    int e = -1, m0 = 0, cnt = 0;
    {
        int acc = 0, prev = 0;
        for (int i = 0; i < NE; ++i) {
            int end = expert_offsets[i];
            int c = end - prev;
            int t = (c + FBM - 1) / FBM;
            if (mt < acc + t) {
                e = i; m0 = prev + (mt - acc) * FBM;
                cnt = end - m0; if (cnt > FBM) cnt = FBM;
                break;
            }
            acc += t; prev = end;
        }
    }
    if (e < 0) return;

    const int tid = threadIdx.x;
    if (tid < FBM) {
        int idx = (tid < cnt) ? (m0 + tid) : m0;
        int p = sorted_scattered_idxs[idx];
        s_tok[tid]  = p;
        s_gate[tid] = gates[p];
    }
    __syncthreads();

    const int ch  = tid & 7;
    const int r0  = tid >> 3;
    const int sch = ch ^ (r0 & 7);
    const float* wbase = weight + (size_t)e * DOUT * DIN;
    const float* ap[4]; const float* bp[4];
    #pragma unroll
    for (int i = 0; i < 4; ++i) {
        int r = r0 + 32 * i;
        ap[i] = inputs + (size_t)(s_tok[r] >> 1) * DIN + ch * 8;
        bp[i] = wbase + (size_t)(n0 + r) * DIN + ch * 8;
    }
    u16* aw = &As[r0 * FBK + sch * 8];
    u16* bw = &Bs[r0 * FBK + sch * 8];

    const int wid = tid >> 6, lane = tid & 63;
    const int wm = (wid >> 1) * 64, wn = (wid & 1) * 64;
    const int g  = lane >> 4, lr = lane & 15;

    f32x4 acc[4][4];
    #pragma unroll
    for (int i = 0; i < 4; ++i)
        #pragma unroll
        for (int j = 0; j < 4; ++j) acc[i][j] = (f32x4)0.0f;

    float4 pa[4][2], pb[4][2];
    #pragma unroll
    for (int i = 0; i < 4; ++i) {
        pa[i][0] = *(const float4*)(ap[i] + 0); pa[i][1] = *(const float4*)(ap[i] + 4);
        pb[i][0] = *(const float4*)(bp[i] + 0); pb[i][1] = *(const float4*)(bp[i] + 4);
    }
    for (int kt = 0; kt < DIN / FBK; ++kt) {
        __syncthreads();
        #pragma unroll
        for (int i = 0; i < 4; ++i) {
            uint4 va, vb;
            va.x = pack2rn(pa[i][0].x, pa[i][0].y); va.y = pack2rn(pa[i][0].z, pa[i][0].w);
            va.z = pack2rn(pa[i][1].x, pa[i][1].y); va.w = pack2rn(pa[i][1].z, pa[i][1].w);
            *(uint4*)(aw + i * 32 * FBK) = va;
            vb.x = pack2rn(pb[i][0].x, pb[i][0].y); vb.y = pack2rn(pb[i][0].z, pb[i][0].w);
            vb.z = pack2rn(pb[i][1].x, pb[i][1].y); vb.w = pack2rn(pb[i][1].z, pb[i][1].w);
            *(uint4*)(bw + i * 32 * FBK) = vb;
        }
        __syncthreads();
        if (kt + 1 < DIN / FBK) {
            const int kof = (kt + 1) * FBK;
            #pragma unroll
            for (int i = 0; i < 4; ++i) {
                pa[i][0] = *(const float4*)(ap[i] + kof); pa[i][1] = *(const float4*)(ap[i] + kof + 4);
                pb[i][0] = *(const float4*)(bp[i] + kof); pb[i][1] = *(const float4*)(bp[i] + kof + 4);
            }
        }
        #pragma unroll
        for (int ks = 0; ks < 2; ++ks) {
            bf16x8 a[4], b[4];
            #pragma unroll
            for (int i = 0; i < 4; ++i) {
                int ra = wm + i * 16 + lr; int ca = (ks * 4 + g) ^ (ra & 7);
                a[i] = *(const bf16x8*)(&As[ra * FBK + ca * 8]);
                int rb = wn + i * 16 + lr; int cb = (ks * 4 + g) ^ (rb & 7);
                b[i] = *(const bf16x8*)(&Bs[rb * FBK + cb * 8]);
            }
            #pragma unroll
            for (int i = 0; i < 4; ++i)
                #pragma unroll
                for (int j = 0; j < 4; ++j)
                    acc[i][j] = __builtin_amdgcn_mfma_f32_16x16x32_bf16(a[i], b[j], acc[i][j], 0, 0, 0);
        }
    }
    #pragma unroll
    for (int i = 0; i < 4; ++i) {
        #pragma unroll
        for (int j2 = 0; j2 < 4; ++j2) {
            int lrow = wm + i * 16 + g * 4 + j2;
            if (lrow < cnt) {
                int   p  = s_tok[lrow];
                float gf = s_gate[lrow];
                float* orow = out + (size_t)(p >> 1) * DOUT + n0 + wn;
                #pragma unroll
                for (int nf = 0; nf < 4; ++nf)
                    atomicAdd(orow + nf * 16 + lr, gf * acc[i][nf][j2]);
            }
        }
    }
}

extern "C" void kernel_launch(void* const* d_in, const int* in_sizes, int n_in,
                              void* d_out, int out_size, void* d_ws, size_t ws_size,
                              hipStream_t stream) {
    const float* inputs  = (const float*)d_in[0];
    const float* weight  = (const float*)d_in[1];
    const int*   ssi     = (const int*)d_in[4];
    const int*   eoff    = (const int*)d_in[6];
    const float* gates   = (const float*)d_in[7];
    float* out = (float*)d_out;

    hipMemsetAsync(out, 0, (size_t)out_size * sizeof(float), stream);

    const size_t need = ((size_t)WEL + (size_t)XEL) * sizeof(u16);  // 75.5 MB
    if (ws_size >= need) {
        u16* wbf = (u16*)d_ws;
        u16* xbf = wbf + (size_t)WEL;
        cvt_bf16<<<2048, 256, 0, stream>>>(weight, inputs, wbf, xbf);
        moe_gemm8<<<NBLK, 512, 0, stream>>>(xbf, wbf, ssi, eoff, gates, out);
    } else {
        dim3 grid(DOUT / FBM, NK / FBM + NE);
        moe_gemm_fused<<<grid, 256, 0, stream>>>(inputs, weight, ssi, eoff, gates, out);
    }
}